// Round 3
// baseline (3038.549 us; speedup 1.0000x reference)
//
#include <hip/hip_runtime.h>
#include <stdint.h>

#define NNODES 10000
#define NEDGES 160000
#define DIM    2500
#define NCLS   16
#define KP     2560          // padded feature dim (40 * 64)
#define MP     10240         // padded rows (80 * 128)
#define K2     5120          // concat K for layer GEMMs
#define GN     20            // N tiles (2560 / 128)
#define KT_SEG 40            // K-steps per segment (2560 / 64)

typedef __attribute__((ext_vector_type(8))) short short8;
typedef __attribute__((ext_vector_type(4))) float f32x4;
typedef __attribute__((address_space(3))) void as3_void;
typedef const __attribute__((address_space(1))) void as1_cvoid;

__device__ __forceinline__ unsigned short f2bf(float f) {
    unsigned u = __float_as_uint(f);
    u += 0x7FFFu + ((u >> 16) & 1u);            // RNE
    return (unsigned short)(u >> 16);
}
__device__ __forceinline__ float bf2f(unsigned short s) {
    return __uint_as_float(((unsigned)s) << 16);
}

// ---------------- CSR build ----------------
// edge_index is INT32: JAX without x64 silently downcasts jnp.int64 -> int32.
// (Round-1 crash forensics: int64 reads combined adjacent int32 pairs -> huge
//  indices -> OOB atomicAdd -> HSA abort. int32 is confirmed correct.)
__global__ void k_deg(const int* __restrict__ ei, int* __restrict__ deg) {
    int e = blockIdx.x * blockDim.x + threadIdx.x;
    if (e < NEDGES) atomicAdd(&deg[ei[NEDGES + e]], 1);
}

__global__ void k_scan(const int* __restrict__ deg, int* __restrict__ off) {
    __shared__ int s[1024];
    __shared__ int carryS;
    int t = threadIdx.x;
    if (t == 0) carryS = 0;
    __syncthreads();
    for (int c = 0; c < NNODES; c += 1024) {
        int i = c + t;
        int v = (i < NNODES) ? deg[i] : 0;
        s[t] = v;
        __syncthreads();
        for (int o = 1; o < 1024; o <<= 1) {
            int add = (t >= o) ? s[t - o] : 0;
            __syncthreads();
            s[t] += add;
            __syncthreads();
        }
        int base = carryS;
        if (i < NNODES) off[i] = base + s[t] - v;   // exclusive
        __syncthreads();
        if (t == 1023) carryS += s[1023];
        __syncthreads();
    }
    if (t == 0) off[NNODES] = carryS;
}

__global__ void k_fill(const int* __restrict__ ei, const int* __restrict__ off,
                       int* __restrict__ cur, int* __restrict__ csr) {
    int e = blockIdx.x * blockDim.x + threadIdx.x;
    if (e < NEDGES) {
        int s = ei[e];
        int d = ei[NEDGES + e];
        int p = atomicAdd(&cur[d], 1);
        csr[off[d] + p] = s;
    }
}

// ---------------- x -> hi/lo bf16 planes (padded, pads zeroed) ----------------
__global__ void k_cvt_x(const float* __restrict__ x,
                        unsigned short* __restrict__ hi, unsigned short* __restrict__ lo) {
    long long idx = (long long)blockIdx.x * blockDim.x + threadIdx.x;  // float4 index
    const int C4 = KP / 4;                                             // 640
    if (idx >= (long long)MP * C4) return;
    int row = (int)(idx / C4), c4 = (int)(idx % C4);
    int k = c4 * 4;
    float vv[4] = {0.f, 0.f, 0.f, 0.f};
    if (row < NNODES && k < DIM) {
        float4 v = *(const float4*)(x + (size_t)row * DIM + k);
        vv[0] = v.x; vv[1] = v.y; vv[2] = v.z; vv[3] = v.w;
    }
    unsigned hw[2], lw[2];
    for (int j = 0; j < 2; j++) {
        unsigned short h0 = f2bf(vv[2*j]);     unsigned short l0 = f2bf(vv[2*j]   - bf2f(h0));
        unsigned short h1 = f2bf(vv[2*j+1]);   unsigned short l1 = f2bf(vv[2*j+1] - bf2f(h1));
        hw[j] = (unsigned)h0 | ((unsigned)h1 << 16);
        lw[j] = (unsigned)l0 | ((unsigned)l1 << 16);
    }
    *(uint2*)(hi + (size_t)row * KP + k) = make_uint2(hw[0], hw[1]);
    *(uint2*)(lo + (size_t)row * KP + k) = make_uint2(lw[0], lw[1]);
}

// ---------------- mean aggregation over in-neighbors ----------------
__global__ __launch_bounds__(320) void k_agg(
    const unsigned short* __restrict__ shi, const unsigned short* __restrict__ slo,
    const int* __restrict__ off, const int* __restrict__ csr, const int* __restrict__ deg,
    unsigned short* __restrict__ mhi, unsigned short* __restrict__ mlo) {
    int d = blockIdx.x;
    int t = threadIdx.x;                     // owns 8 elems at k = t*8
    int s0 = off[d], s1 = off[d + 1];
    float acc[8];
    #pragma unroll
    for (int i = 0; i < 8; i++) acc[i] = 0.f;
    for (int e = s0; e < s1; e++) {
        int s = csr[e];
        uint4 hv = *((const uint4*)(shi + (size_t)s * KP) + t);
        uint4 lv = *((const uint4*)(slo + (size_t)s * KP) + t);
        unsigned hu[4] = {hv.x, hv.y, hv.z, hv.w};
        unsigned lu[4] = {lv.x, lv.y, lv.z, lv.w};
        #pragma unroll
        for (int j = 0; j < 4; j++) {
            acc[2*j]   += bf2f((unsigned short)(hu[j] & 0xFFFFu)) + bf2f((unsigned short)(lu[j] & 0xFFFFu));
            acc[2*j+1] += bf2f((unsigned short)(hu[j] >> 16))     + bf2f((unsigned short)(lu[j] >> 16));
        }
    }
    int dg = deg[d];
    float inv = 1.0f / (float)(dg > 1 ? dg : 1);
    unsigned oh[4], ol[4];
    #pragma unroll
    for (int j = 0; j < 4; j++) {
        float m0 = acc[2*j] * inv, m1 = acc[2*j+1] * inv;
        unsigned short h0 = f2bf(m0); unsigned short l0 = f2bf(m0 - bf2f(h0));
        unsigned short h1 = f2bf(m1); unsigned short l1 = f2bf(m1 - bf2f(h1));
        oh[j] = (unsigned)h0 | ((unsigned)h1 << 16);
        ol[j] = (unsigned)l0 | ((unsigned)l1 << 16);
    }
    *((uint4*)(mhi + (size_t)d * KP) + t) = make_uint4(oh[0], oh[1], oh[2], oh[3]);
    *((uint4*)(mlo + (size_t)d * KP) + t) = make_uint4(ol[0], ol[1], ol[2], ol[3]);
}

// ---------------- W (K x N fp32) -> WT (N x K2, hi/lo bf16), transposed ----------------
__global__ __launch_bounds__(256) void k_cvt_w(const float* __restrict__ W,
                                               unsigned short* __restrict__ wth,
                                               unsigned short* __restrict__ wtl, int seg) {
    __shared__ float tile[64][65];
    int k0 = blockIdx.x * 64, n0 = blockIdx.y * 64;
    int t = threadIdx.x;
    for (int j = 0; j < 16; j++) {
        int lin = t + j * 256;
        int kk = lin >> 6, nn = lin & 63;
        int gk = k0 + kk, gn = n0 + nn;
        tile[kk][nn] = (gk < DIM && gn < DIM) ? W[(size_t)gk * DIM + gn] : 0.f;
    }
    __syncthreads();
    for (int j = 0; j < 16; j++) {
        int lin = t + j * 256;
        int nn = lin >> 6, kk = lin & 63;
        float v = tile[kk][nn];
        unsigned short h = f2bf(v);
        unsigned short l = f2bf(v - bf2f(h));
        size_t o = (size_t)(n0 + nn) * K2 + (size_t)seg * KP + (k0 + kk);
        wth[o] = h;
        wtl[o] = l;
    }
}

// ---------------- fused GEMM: O = relu(A_self*W_self + A_mean*W_neigh + bias) -> hi/lo ----------------
__global__ __launch_bounds__(256, 2) void k_gemm(
    const unsigned short* __restrict__ AsH, const unsigned short* __restrict__ AsL,
    const unsigned short* __restrict__ AmH, const unsigned short* __restrict__ AmL,
    const unsigned short* __restrict__ BH,  const unsigned short* __restrict__ BL,
    const float* __restrict__ bias,
    unsigned short* __restrict__ OH, unsigned short* __restrict__ OL, int ktiles) {
    __shared__ __align__(16) unsigned short lds[4 * 128 * 64];   // Ahi|Alo|Bhi|Blo, 64 KiB
    const int tid = threadIdx.x;
    const int wave = tid >> 6, lane = tid & 63;
    const int g = blockIdx.x;
    const int tm = g / GN, tn = g % GN;

    // staging coords: dest chunk = tid&7, source chunk XOR-swizzled (involution)
    const int srow = tid >> 3;                      // 0..31
    const int sc = (tid & 7) ^ (srow & 7);
    size_t aOff[4], bOff[4];
    #pragma unroll
    for (int j = 0; j < 4; j++) {
        int row = j * 32 + srow;
        aOff[j] = (size_t)(tm * 128 + row) * KP + sc * 8;
        bOff[j] = (size_t)(tn * 128 + row) * K2 + sc * 8;
    }
    char* ldsB = (char*)lds;
    const int dstBase = wave * 1024;

    const int wr = wave >> 1, wc = wave & 1;
    const int frow = lane & 15, fk = lane >> 4;
    int aFo[2][4], bFo[2][4];
    #pragma unroll
    for (int s = 0; s < 2; s++) {
        #pragma unroll
        for (int i = 0; i < 4; i++) {
            int ra = wr * 64 + i * 16 + frow;
            aFo[s][i] = ra * 64 + (((s * 4 + fk) ^ (ra & 7)) * 8);
            int rb = wc * 64 + i * 16 + frow;
            bFo[s][i] = rb * 64 + (((s * 4 + fk) ^ (rb & 7)) * 8);
        }
    }

    f32x4 acc[4][4];
    #pragma unroll
    for (int i = 0; i < 4; i++)
        #pragma unroll
        for (int j = 0; j < 4; j++) acc[i][j] = (f32x4){0.f, 0.f, 0.f, 0.f};

    for (int kt = 0; kt < ktiles; kt++) {
        const unsigned short *Ah, *Al;
        int kA;
        if (kt < KT_SEG) { Ah = AsH; Al = AsL; kA = kt * 64; }
        else             { Ah = AmH; Al = AmL; kA = (kt - KT_SEG) * 64; }
        const int kB = kt * 64;
        #pragma unroll
        for (int j = 0; j < 4; j++) {
            __builtin_amdgcn_global_load_lds((as1_cvoid*)(Ah + aOff[j] + kA),
                (as3_void*)(ldsB + 0 * 16384 + j * 4096 + dstBase), 16, 0, 0);
            __builtin_amdgcn_global_load_lds((as1_cvoid*)(Al + aOff[j] + kA),
                (as3_void*)(ldsB + 1 * 16384 + j * 4096 + dstBase), 16, 0, 0);
            __builtin_amdgcn_global_load_lds((as1_cvoid*)(BH + bOff[j] + kB),
                (as3_void*)(ldsB + 2 * 16384 + j * 4096 + dstBase), 16, 0, 0);
            __builtin_amdgcn_global_load_lds((as1_cvoid*)(BL + bOff[j] + kB),
                (as3_void*)(ldsB + 3 * 16384 + j * 4096 + dstBase), 16, 0, 0);
        }
        __syncthreads();
        #pragma unroll
        for (int s = 0; s < 2; s++) {
            short8 ah[4], al[4], bh[4], bl[4];
            #pragma unroll
            for (int i = 0; i < 4; i++) {
                ah[i] = *(const short8*)&lds[0 * 8192 + aFo[s][i]];
                al[i] = *(const short8*)&lds[1 * 8192 + aFo[s][i]];
                bh[i] = *(const short8*)&lds[2 * 8192 + bFo[s][i]];
                bl[i] = *(const short8*)&lds[3 * 8192 + bFo[s][i]];
            }
            #pragma unroll
            for (int mi = 0; mi < 4; mi++)
                #pragma unroll
                for (int ni = 0; ni < 4; ni++) {
                    acc[mi][ni] = __builtin_amdgcn_mfma_f32_16x16x32_bf16(ah[mi], bh[ni], acc[mi][ni], 0, 0, 0);
                    acc[mi][ni] = __builtin_amdgcn_mfma_f32_16x16x32_bf16(ah[mi], bl[ni], acc[mi][ni], 0, 0, 0);
                    acc[mi][ni] = __builtin_amdgcn_mfma_f32_16x16x32_bf16(al[mi], bh[ni], acc[mi][ni], 0, 0, 0);
                }
        }
        __syncthreads();
    }

    // epilogue: bias + relu + hi/lo decompose, zero pad cols
    const int r4 = (lane >> 4) * 4;
    #pragma unroll
    for (int ni = 0; ni < 4; ni++) {
        int gn = tn * 128 + wc * 64 + ni * 16 + (lane & 15);
        bool valid = gn < DIM;
        float bv = valid ? bias[gn] : 0.f;
        #pragma unroll
        for (int mi = 0; mi < 4; mi++) {
            int gmBase = tm * 128 + wr * 64 + mi * 16 + r4;
            #pragma unroll
            for (int rg = 0; rg < 4; rg++) {
                float v = acc[mi][ni][rg] + bv;
                v = fmaxf(v, 0.f);
                if (!valid) v = 0.f;
                size_t o = (size_t)(gmBase + rg) * KP + gn;
                unsigned short h = f2bf(v);
                OH[o] = h;
                OL[o] = f2bf(v - bf2f(h));
            }
        }
    }
}

// ---------------- final head: out = h @ Wc2 + bc2 ----------------
__global__ __launch_bounds__(256) void k_head(
    const unsigned short* __restrict__ HH, const unsigned short* __restrict__ HL,
    const float* __restrict__ W, const float* __restrict__ b, float* __restrict__ out) {
    const int m = blockIdx.x;
    const int t = threadIdx.x;
    const unsigned short* rh = HH + (size_t)m * KP;
    const unsigned short* rl = HL + (size_t)m * KP;
    float acc[NCLS];
    #pragma unroll
    for (int c = 0; c < NCLS; c++) acc[c] = 0.f;
    for (int j = 0; j < 5; j++) {
        int k0 = (j * 256 + t) * 2;
        if (k0 >= DIM) continue;
        unsigned hv = *(const unsigned*)(rh + k0);
        unsigned lv = *(const unsigned*)(rl + k0);
        float v0 = bf2f((unsigned short)(hv & 0xFFFFu)) + bf2f((unsigned short)(lv & 0xFFFFu));
        float v1 = bf2f((unsigned short)(hv >> 16)) + bf2f((unsigned short)(lv >> 16));
        const float* w0 = W + (size_t)k0 * NCLS;
        #pragma unroll
        for (int c = 0; c < NCLS; c++) acc[c] += v0 * w0[c] + v1 * w0[NCLS + c];
    }
    #pragma unroll
    for (int o = 32; o > 0; o >>= 1)
        #pragma unroll
        for (int c = 0; c < NCLS; c++) acc[c] += __shfl_down(acc[c], o);
    __shared__ float red[4][NCLS];
    if ((t & 63) == 0)
        #pragma unroll
        for (int c = 0; c < NCLS; c++) red[t >> 6][c] = acc[c];
    __syncthreads();
    if (t < NCLS)
        out[(size_t)m * NCLS + t] = red[0][t] + red[1][t] + red[2][t] + red[3][t] + b[t];
}

extern "C" void kernel_launch(void* const* d_in, const int* in_sizes, int n_in,
                              void* d_out, int out_size, void* d_ws, size_t ws_size,
                              hipStream_t stream) {
    const float* x   = (const float*)d_in[0];
    const int* ei    = (const int*)d_in[1];   // int32! (JAX default x64-disabled)
    const float* W1s = (const float*)d_in[2];
    const float* W1n = (const float*)d_in[3];
    const float* b1  = (const float*)d_in[4];
    const float* W2s = (const float*)d_in[5];
    const float* W2n = (const float*)d_in[6];
    const float* b2  = (const float*)d_in[7];
    const float* Wc1 = (const float*)d_in[8];
    const float* bc1 = (const float*)d_in[9];
    const float* Wc2 = (const float*)d_in[10];
    const float* bc2 = (const float*)d_in[11];

    char* p = (char*)d_ws;
    auto nxt = [&](size_t bytes) -> char* {
        char* r = p;
        p += (bytes + 255) & ~(size_t)255;
        return r;
    };
    const size_t PLB = (size_t)MP * KP * sizeof(unsigned short);   // 52.4 MB
    unsigned short* F0H = (unsigned short*)nxt(PLB);
    unsigned short* F0L = (unsigned short*)nxt(PLB);
    unsigned short* F1H = (unsigned short*)nxt(PLB);
    unsigned short* F1L = (unsigned short*)nxt(PLB);
    unsigned short* FMH = (unsigned short*)nxt(PLB);
    unsigned short* FML = (unsigned short*)nxt(PLB);
    const size_t WTB = (size_t)KP * K2 * sizeof(unsigned short);   // 26.2 MB
    unsigned short* WTH = (unsigned short*)nxt(WTB);
    unsigned short* WTL = (unsigned short*)nxt(WTB);
    int* deg = (int*)nxt(NNODES * 4);
    int* off = (int*)nxt((NNODES + 1) * 4);
    int* cur = (int*)nxt(NNODES * 4);
    int* csr = (int*)nxt(NEDGES * 4);

    hipMemsetAsync(deg, 0, NNODES * 4, stream);
    hipMemsetAsync(cur, 0, NNODES * 4, stream);

    k_deg<<<(NEDGES + 255) / 256, 256, 0, stream>>>(ei, deg);
    k_scan<<<1, 1024, 0, stream>>>(deg, off);
    k_fill<<<(NEDGES + 255) / 256, 256, 0, stream>>>(ei, off, cur, csr);

    k_cvt_x<<<(int)(((size_t)MP * (KP / 4) + 255) / 256), 256, 0, stream>>>(x, F0H, F0L);

    // layer 1
    k_agg<<<NNODES, 320, 0, stream>>>(F0H, F0L, off, csr, deg, FMH, FML);
    k_cvt_w<<<dim3(40, 40), 256, 0, stream>>>(W1s, WTH, WTL, 0);
    k_cvt_w<<<dim3(40, 40), 256, 0, stream>>>(W1n, WTH, WTL, 1);
    k_gemm<<<80 * GN, 256, 0, stream>>>(F0H, F0L, FMH, FML, WTH, WTL, b1, F1H, F1L, 80);

    // layer 2
    k_agg<<<NNODES, 320, 0, stream>>>(F1H, F1L, off, csr, deg, FMH, FML);
    k_cvt_w<<<dim3(40, 40), 256, 0, stream>>>(W2s, WTH, WTL, 0);
    k_cvt_w<<<dim3(40, 40), 256, 0, stream>>>(W2n, WTH, WTL, 1);
    k_gemm<<<80 * GN, 256, 0, stream>>>(F1H, F1L, FMH, FML, WTH, WTL, b2, F0H, F0L, 80);

    // classifier hidden (ktiles=40 -> mean operands never read; pass valid ptrs anyway)
    k_cvt_w<<<dim3(40, 40), 256, 0, stream>>>(Wc1, WTH, WTL, 0);
    k_gemm<<<80 * GN, 256, 0, stream>>>(F0H, F0L, F0H, F0L, WTH, WTL, bc1, F1H, F1L, 40);

    // head
    k_head<<<NNODES, 256, 0, stream>>>(F1H, F1L, Wc2, bc2, (float*)d_out);
}